// Round 1
// baseline (100.259 us; speedup 1.0000x reference)
//
#include <hip/hip_runtime.h>
#include <stdint.h>
#include <stddef.h>

#define B_   8
#define N_   256
#define H_   128
#define E_   128
#define MIDC 128
#define INZ  256
#define BIGN 1000000.0f

typedef float f32x4 __attribute__((ext_vector_type(4)));
typedef short bf16x8 __attribute__((ext_vector_type(8)));

static __device__ __forceinline__ short f2bf(float f) {
    unsigned u = __builtin_bit_cast(unsigned, f);
    unsigned r = (u + 0x7FFFu + ((u >> 16) & 1u)) >> 16;
    return (short)r;
}

// ---------------------------------------------------------------------------
// prep: msg1 = z@W1+b1 ; m2g = z@W2+b2+graph@Wg+bg ; zo1 = z@Wo1+bo1
// also (block 0): We^T -> bf16, XOR-swizzled for main-kernel B-frag reads
// 256 blocks x 256 threads, 8 rows/block, 4 rows per thread-half
// ---------------------------------------------------------------------------
__global__ __launch_bounds__(256) void prep_kernel(
    const float* __restrict__ node, const float* __restrict__ hidden,
    const float* __restrict__ gf,
    const float* __restrict__ W1, const float* __restrict__ b1,
    const float* __restrict__ W2, const float* __restrict__ b2,
    const float* __restrict__ Wg, const float* __restrict__ bg,
    const float* __restrict__ Wo1, const float* __restrict__ bo1,
    const float* __restrict__ We,
    float* __restrict__ msg1, float* __restrict__ m2g,
    float* __restrict__ zo1, unsigned short* __restrict__ weT)
{
    __shared__ float zs[8][INZ];
    const int t  = threadIdx.x;
    const int r0 = blockIdx.x * 8;        // global row base (row = b*N + n)
    const int b  = r0 >> 8;

    // stage z rows: z = concat(node_fts, hidden)
    for (int idx = t; idx < 8 * INZ; idx += 256) {
        int r = idx >> 8, k = idx & 255;
        int row = r0 + r;
        zs[r][k] = (k < H_) ? node[(size_t)row * H_ + k]
                            : hidden[(size_t)row * H_ + (k - H_)];
    }
    // We^T bf16, pre-swizzled (byte ^ ((rowB&7)<<4) -> short ^ ((rowB&7)<<3))
    if (blockIdx.x == 0) {
        for (int e = t; e < 128 * 128; e += 256) {
            int n = e >> 7, k = e & 127;
            weT[(n * 128 + k) ^ ((n & 7) << 3)] =
                (unsigned short)f2bf(We[k * 128 + n]);
        }
    }
    __syncthreads();

    const int col = t & 127;
    const int rg  = t >> 7;              // 0..1, 4 rows each
    float a1[4] = {0, 0, 0, 0}, a2[4] = {0, 0, 0, 0}, ao[4] = {0, 0, 0, 0};

#pragma unroll 4
    for (int k = 0; k < INZ; ++k) {
        float w1 = W1[k * 128 + col];
        float w2 = W2[k * 128 + col];
        float wo = Wo1[k * 128 + col];
#pragma unroll
        for (int rr = 0; rr < 4; ++rr) {
            float zv = zs[rg * 4 + rr][k];
            a1[rr] = fmaf(zv, w1, a1[rr]);
            a2[rr] = fmaf(zv, w2, a2[rr]);
            ao[rr] = fmaf(zv, wo, ao[rr]);
        }
    }
    float mg = bg[col];
#pragma unroll 4
    for (int g = 0; g < 128; ++g)
        mg = fmaf(gf[b * 128 + g], Wg[g * 128 + col], mg);

    const float bb1 = b1[col], bb2 = b2[col], bbo = bo1[col];
#pragma unroll
    for (int rr = 0; rr < 4; ++rr) {
        size_t row = (size_t)(r0 + rg * 4 + rr);
        msg1[row * 128 + col] = a1[rr] + bb1;
        m2g[row * 128 + col]  = a2[rr] + bb2 + mg;
        zo1[row * 128 + col]  = ao[rr] + bbo;
    }
}

// ---------------------------------------------------------------------------
// main: per block (b, 4 j's): loop i-chunks of 32 -> 128x128 GEMM tile
// (edge@We in bf16 MFMA), masked-max epilogue over i, fused final
// relu(zo1 + (red+msg1+be)@Wo2 + bo2)
// ---------------------------------------------------------------------------
__global__ __launch_bounds__(256, 2) void pgn_main(
    const float* __restrict__ edge, const float* __restrict__ adj,
    const float* __restrict__ msg1, const float* __restrict__ m2g,
    const float* __restrict__ zo1,
    const unsigned short* __restrict__ weT,
    const float* __restrict__ be, const float* __restrict__ Wo2,
    const float* __restrict__ bo2, float* __restrict__ out)
{
    __shared__ __align__(16) short atile[128 * 128];   // 32KB: WeT staging, then edge tiles
    __shared__ __align__(16) float adjt[128];          // 32 i x 4 j
    __shared__ __align__(16) float redb[512];          // 4 j x 128 cols

    const int t    = threadIdx.x;
    const int lane = t & 63, wid = t >> 6;
    const int wr   = wid >> 1, wn = wid & 1;
    const int hi   = lane >> 4, c15 = lane & 15;
    const int blk  = blockIdx.x;
    const int b    = blk >> 6, jt = blk & 63;
    const int j0   = jt * 4;

    // ---- stage WeT (pre-swizzled) into LDS, preload B fragments ----
    {
        const uint4* src = (const uint4*)weT;
        uint4* dst = (uint4*)atile;
#pragma unroll
        for (int q = 0; q < 8; ++q) dst[t + 256 * q] = src[t + 256 * q];
    }
    __syncthreads();
    bf16x8 bfr[4][4];
#pragma unroll
    for (int n = 0; n < 4; ++n) {
        int rowB = wn * 64 + n * 16 + c15;
#pragma unroll
        for (int ks = 0; ks < 4; ++ks) {
            int a = (rowB * 256 + ks * 64 + hi * 16) ^ ((rowB & 7) << 4);
            bfr[n][ks] = *(const bf16x8*)((const char*)atile + a);
        }
    }
    __syncthreads();

    float rmax[4][4];
#pragma unroll
    for (int n = 0; n < 4; ++n)
#pragma unroll
        for (int rg = 0; rg < 4; ++rg) rmax[n][rg] = -BIGN;

    // staging geometry: thread t covers tile-row sr (= 4i+jj), half sh (64 floats)
    const int sr = t >> 1, sh = t & 1;
    const size_t istep = (size_t)N_ * E_;
    const size_t base0 = (((size_t)(b * N_) + (sr >> 2)) * N_ + (j0 + (sr & 3))) * E_
                         + (size_t)sh * 64;
    const int wbase = sr * 256 + sh * 128;
    const int swz   = (sr & 7) << 4;

    for (int it = 0; it < 8; ++it) {
        const int i0 = it * 32;
        // ---- stage edge tile: global f32 -> bf16 -> swizzled LDS ----
        const float4* src = (const float4*)(edge + base0 + (size_t)i0 * istep);
#pragma unroll
        for (int q = 0; q < 8; ++q) {
            float4 f0 = src[2 * q];
            float4 f1 = src[2 * q + 1];
            bf16x8 s;
            s[0] = f2bf(f0.x); s[1] = f2bf(f0.y); s[2] = f2bf(f0.z); s[3] = f2bf(f0.w);
            s[4] = f2bf(f1.x); s[5] = f2bf(f1.y); s[6] = f2bf(f1.z); s[7] = f2bf(f1.w);
            *(bf16x8*)((char*)atile + ((wbase + q * 16) ^ swz)) = s;
        }
        if (t < 128)
            adjt[t] = adj[(size_t)(b * N_ + i0 + (t >> 2)) * N_ + j0 + (t & 3)];
        __syncthreads();

        // ---- 128x128x128 tile GEMM: 4 K-steps of 32 ----
        f32x4 acc[4][4] = {};
#pragma unroll
        for (int ks = 0; ks < 4; ++ks) {
            bf16x8 af[4];
#pragma unroll
            for (int m = 0; m < 4; ++m) {
                int rowA = wr * 64 + m * 16 + c15;
                int a = (rowA * 256 + ks * 64 + hi * 16) ^ ((rowA & 7) << 4);
                af[m] = *(const bf16x8*)((const char*)atile + a);
            }
#pragma unroll
            for (int m = 0; m < 4; ++m)
#pragma unroll
                for (int n = 0; n < 4; ++n)
                    acc[m][n] = __builtin_amdgcn_mfma_f32_16x16x32_bf16(
                        af[m], bfr[n][ks], acc[m][n], 0, 0, 0);
        }

        // ---- epilogue: masked max over i into running registers ----
#pragma unroll
        for (int m = 0; m < 4; ++m) {
            int i_loc = wr * 16 + m * 4 + hi;                 // tile row >> 2
            f32x4 am = *(const f32x4*)&adjt[i_loc * 4];       // adj for jj=0..3
            const float* mp = m2g + (size_t)(b * N_ + i0 + i_loc) * 128 + wn * 64 + c15;
#pragma unroll
            for (int n = 0; n < 4; ++n) {
                float mv = mp[n * 16];
#pragma unroll
                for (int rg = 0; rg < 4; ++rg) {              // rg == jj
                    float v = acc[m][n][rg] + mv;
                    v = (am[rg] > 0.0f) ? v : -BIGN;
                    rmax[n][rg] = fmaxf(rmax[n][rg], v);
                }
            }
        }
        __syncthreads();   // protect atile/adjt before next stage
    }

    // ---- reduce across hi (lanes) and wr (waves) ----
#pragma unroll
    for (int n = 0; n < 4; ++n)
#pragma unroll
        for (int rg = 0; rg < 4; ++rg) {
            float v = rmax[n][rg];
            v = fmaxf(v, __shfl_xor(v, 16, 64));
            v = fmaxf(v, __shfl_xor(v, 32, 64));
            rmax[n][rg] = v;
        }
    if (wr == 0 && lane < 16) {
#pragma unroll
        for (int n = 0; n < 4; ++n)
#pragma unroll
            for (int rg = 0; rg < 4; ++rg)
                redb[rg * 128 + wn * 64 + n * 16 + c15] = rmax[n][rg];
    }
    __syncthreads();
    if (wr == 1 && lane < 16) {
#pragma unroll
        for (int n = 0; n < 4; ++n)
#pragma unroll
            for (int rg = 0; rg < 4; ++rg) {
                int e = rg * 128 + wn * 64 + n * 16 + c15;
                redb[e] = fmaxf(redb[e], rmax[n][rg]);
            }
    }
    __syncthreads();

    // ---- add j-constant terms: msg1 + be ----
    for (int e = t; e < 512; e += 256) {
        int jj = e >> 7, k = e & 127;
        redb[e] += msg1[(size_t)(b * N_ + j0 + jj) * 128 + k] + be[k];
    }
    __syncthreads();

    // ---- fused output: relu(zo1 + red@Wo2 + bo2), 4 rows x 128 cols ----
    {
        const int col = t & 127;
        const int jh  = t >> 7;
#pragma unroll
        for (int jx = 0; jx < 2; ++jx) {
            int jj = jh * 2 + jx;
            size_t row = (size_t)(b * N_ + j0 + jj);
            float a = 0.0f;
#pragma unroll 8
            for (int k = 0; k < 128; ++k)
                a = fmaf(redb[jj * 128 + k], Wo2[k * 128 + col], a);
            float o = zo1[row * 128 + col] + bo2[col] + a;
            out[row * 128 + col] = fmaxf(o, 0.0f);
        }
    }
}

extern "C" void kernel_launch(void* const* d_in, const int* in_sizes, int n_in,
                              void* d_out, int out_size, void* d_ws, size_t ws_size,
                              hipStream_t stream) {
    const float* node   = (const float*)d_in[0];
    const float* edge   = (const float*)d_in[1];
    const float* gf     = (const float*)d_in[2];
    const float* adj    = (const float*)d_in[3];
    const float* hidden = (const float*)d_in[4];
    const float* W1  = (const float*)d_in[5];
    const float* b1  = (const float*)d_in[6];
    const float* W2  = (const float*)d_in[7];
    const float* b2  = (const float*)d_in[8];
    const float* We  = (const float*)d_in[9];
    const float* be  = (const float*)d_in[10];
    const float* Wg  = (const float*)d_in[11];
    const float* bg  = (const float*)d_in[12];
    const float* Wo1 = (const float*)d_in[13];
    const float* bo1 = (const float*)d_in[14];
    const float* Wo2 = (const float*)d_in[15];
    const float* bo2 = (const float*)d_in[16];
    float* out = (float*)d_out;

    float* msg1 = (float*)d_ws;
    float* m2g  = msg1 + 2048 * 128;
    float* zo1  = m2g + 2048 * 128;
    unsigned short* weT = (unsigned short*)(zo1 + 2048 * 128);

    hipLaunchKernelGGL(prep_kernel, dim3(256), dim3(256), 0, stream,
                       node, hidden, gf, W1, b1, W2, b2, Wg, bg, Wo1, bo1, We,
                       msg1, m2g, zo1, weT);
    hipLaunchKernelGGL(pgn_main, dim3(512), dim3(256), 0, stream,
                       edge, adj, msg1, m2g, zo1, weT, be, Wo2, bo2, out);
}